// Round 6
// baseline (314.630 us; speedup 1.0000x reference)
//
#include <hip/hip_runtime.h>
#include <stdint.h>

#define N_TOK 4096
#define DIM   512
#define BATCH 4
#define BN    (BATCH * N_TOK)
#define JSPLIT 16
#define JT    32                      // j-tile rows
#define IPW   64                      // i-rows per wave
#define IPB   256                     // i-rows per block (4 waves)
#define JITERS (N_TOK / JSPLIT / JT)  // 8

typedef __attribute__((ext_vector_type(4))) float f32x4;

// ---------- kernel 1: fp32 -> fp8(e4m3) convert + per-row sumsq of QUANTIZED values ----------
// sq from quantized values => diagonal d_ii ~ 0 exactly, matching ref's k_ii = 1.
__global__ __launch_bounds__(256) void prep_kernel(
    const float* __restrict__ feat, uint8_t* __restrict__ fb, float* __restrict__ sq)
{
    int row  = (blockIdx.x << 2) + (threadIdx.x >> 6);   // 0..BN-1
    int lane = threadIdx.x & 63;
    const float4* src = (const float4*)(feat + (size_t)row * DIM);
    float4 v0 = src[lane * 2];
    float4 v1 = src[lane * 2 + 1];

    uint w01 = (uint)__builtin_amdgcn_cvt_pk_fp8_f32(v0.x, v0.y, 0, false);
    w01      = (uint)__builtin_amdgcn_cvt_pk_fp8_f32(v0.z, v0.w, (int)w01, true);
    uint w23 = (uint)__builtin_amdgcn_cvt_pk_fp8_f32(v1.x, v1.y, 0, false);
    w23      = (uint)__builtin_amdgcn_cvt_pk_fp8_f32(v1.z, v1.w, (int)w23, true);
    uint2 pk; pk.x = w01; pk.y = w23;
    ((uint2*)(fb + (size_t)row * DIM))[lane] = pk;

    float s = 0.f, f;
    f = __builtin_amdgcn_cvt_f32_fp8((int)w01, 0); s = fmaf(f, f, s);
    f = __builtin_amdgcn_cvt_f32_fp8((int)w01, 1); s = fmaf(f, f, s);
    f = __builtin_amdgcn_cvt_f32_fp8((int)w01, 2); s = fmaf(f, f, s);
    f = __builtin_amdgcn_cvt_f32_fp8((int)w01, 3); s = fmaf(f, f, s);
    f = __builtin_amdgcn_cvt_f32_fp8((int)w23, 0); s = fmaf(f, f, s);
    f = __builtin_amdgcn_cvt_f32_fp8((int)w23, 1); s = fmaf(f, f, s);
    f = __builtin_amdgcn_cvt_f32_fp8((int)w23, 2); s = fmaf(f, f, s);
    f = __builtin_amdgcn_cvt_f32_fp8((int)w23, 3); s = fmaf(f, f, s);

#pragma unroll
    for (int m = 32; m; m >>= 1) s += __shfl_xor(s, m);
    if (lane == 0) sq[row] = s;
}

// async DMA of a 2-row pair (2 x 512B) with XOR-8 16B-chunk swizzle on the GLOBAL side.
__device__ __forceinline__ void dma2(const uint8_t* g, uint8_t* l, int lane, int r)
{
    int loc = lane & 31, h = lane >> 5;
    int sw  = (r + h) & 7;
    const uint8_t* src = g + h * DIM + ((loc ^ sw) << 4);
    __builtin_amdgcn_global_load_lds(
        (const __attribute__((address_space(1))) void*)src,
        (__attribute__((address_space(3))) void*)l, 16, 0, 0);
}

// ---------- kernel 2: flash-style RBF entropy, fp8 MFMA ----------
// grid (N/256, B, 16) = 1024 blocks (4/CU = 16 waves/CU = 4 waves/SIMD at 128 VGPR).
// Wave: 64 i-rows resident (4 strips, 128 VGPR fp8 A), sweeps 32-row j-tiles
// => 64 MACs per LDS byte.  e = min(g/tau^2 - (sqi+sqj)/(2 tau^2), 0); k=exp(e).
__global__ __launch_bounds__(256, 4) void entropy_kernel(
    const uint8_t* __restrict__ fb, const float* __restrict__ sq,
    const float* __restrict__ temp,
    float* __restrict__ Sp, float* __restrict__ Tp)
{
    __shared__ __align__(16) uint8_t Bs[2][JT * DIM];    // 2 x 16KB double buffer

    const int t    = threadIdx.x;
    const int w    = t >> 6;
    const int lane = t & 63;
    const int q    = lane >> 4;
    const int c16  = lane & 15;
    const int q1   = q & 1, q2 = q >> 1;
    const int s8   = c16 & 7;

    const int batch  = blockIdx.y;
    const int jh     = blockIdx.z;
    const int iw     = blockIdx.x * IPB + w * IPW;
    const int jstart = jh * (N_TOK / JSPLIT);
    const size_t rowbase = (size_t)batch * N_TOK;

    const float tau    = temp[0];
    const float inv2t2 = 0.5f / (tau * tau);
    const float cg     = 1.0f / (tau * tau);

    // A fragments: 4 strips x 16 k-chunks, 8B fp8 each = 128 VGPR
    long afrag[4][16];
#pragma unroll
    for (int s = 0; s < 4; ++s) {
        const uint2* ap = (const uint2*)(fb + (rowbase + iw + s * 16 + c16) * DIM);
#pragma unroll
        for (int kc = 0; kc < 16; ++kc) {
            uint2 v = ap[kc * 4 + q];
            afrag[s][kc] = (long)(((unsigned long long)v.y << 32) | v.x);
        }
    }
    float pi[4][4];
#pragma unroll
    for (int s = 0; s < 4; ++s)
#pragma unroll
        for (int r = 0; r < 4; ++r)
            pi[s][r] = -sq[rowbase + iw + s * 16 + q * 4 + r] * inv2t2;

    float S[4][4], T[4][4];
#pragma unroll
    for (int s = 0; s < 4; ++s)
#pragma unroll
        for (int r = 0; r < 4; ++r) { S[s][r] = 0.f; T[s][r] = 0.f; }

    // stage tile 0 (each wave DMAs 4 row-pairs)
#pragma unroll
    for (int rr = 0; rr < 4; ++rr) {
        int r = w * 8 + rr * 2;
        dma2(fb + (rowbase + jstart + r) * DIM, &Bs[0][r * DIM], lane, r);
    }
    __syncthreads();

    int cur = 0;
    for (int it = 0; it < JITERS; ++it) {
        const int jb = jstart + it * JT;
        if (it + 1 < JITERS) {                            // async prefetch next tile
#pragma unroll
            for (int rr = 0; rr < 4; ++rr) {
                int r = w * 8 + rr * 2;
                dma2(fb + (rowbase + jb + JT + r) * DIM, &Bs[cur ^ 1][r * DIM], lane, r);
            }
        }
        float pj0 = -sq[rowbase + jb + c16] * inv2t2;
        float pj1 = -sq[rowbase + jb + 16 + c16] * inv2t2;

#pragma unroll
        for (int jsub = 0; jsub < 2; ++jsub) {
            const uint8_t* Brow = &Bs[cur][(jsub * 16 + c16) * DIM] + (q1 << 3);
            f32x4 acc[4] = {{0,0,0,0},{0,0,0,0},{0,0,0,0},{0,0,0,0}};
#pragma unroll
            for (int kc = 0; kc < 16; ++kc) {
                int off = ((kc * 2 + q2) ^ s8) << 4;      // phys 16B chunk, +q1*8 in Brow
                long b  = *(const long*)(Brow + off);
#pragma unroll
                for (int s = 0; s < 4; ++s)
                    acc[s] = __builtin_amdgcn_mfma_f32_16x16x32_fp8_fp8(
                                 afrag[s][kc], b, acc[s], 0, 0, 0);
            }
            float pj = jsub ? pj1 : pj0;
#pragma unroll
            for (int s = 0; s < 4; ++s)
#pragma unroll
                for (int r = 0; r < 4; ++r) {
                    float e = fminf(fmaf(acc[s][r], cg, pi[s][r] + pj), 0.f);
                    float k = __expf(e);
                    S[s][r] += k;
                    T[s][r] = fmaf(k, e, T[s][r]);
                }
        }
        __syncthreads();                                  // prefetch landed; cur reads done
        cur ^= 1;
    }

    // reduce over the 16 j-columns (c16 lanes)
#pragma unroll
    for (int m = 1; m < 16; m <<= 1)
#pragma unroll
        for (int s = 0; s < 4; ++s)
#pragma unroll
            for (int r = 0; r < 4; ++r) {
                S[s][r] += __shfl_xor(S[s][r], m);
                T[s][r] += __shfl_xor(T[s][r], m);
            }

    if (c16 == 0) {
#pragma unroll
        for (int s = 0; s < 4; ++s)
#pragma unroll
            for (int r = 0; r < 4; ++r) {
                size_t idx = (size_t)jh * BN + rowbase + iw + s * 16 + q * 4 + r;
                Sp[idx] = S[s][r];
                Tp[idx] = T[s][r];
            }
    }
}

// ---------- kernel 3: combine partials, entropy -> sigmoid -> scale features ----------
__global__ __launch_bounds__(256) void finalize_kernel(
    const float* __restrict__ feat, const float* __restrict__ Sp,
    const float* __restrict__ Tp, const float* __restrict__ tgt,
    const float* __restrict__ temp, float* __restrict__ out)
{
    int row  = (blockIdx.x << 2) + (threadIdx.x >> 6);   // global row 0..BN-1
    int lane = threadIdx.x & 63;
    float S = 0.0f, T = 0.0f;
#pragma unroll
    for (int j = 0; j < JSPLIT; ++j) {
        S += Sp[(size_t)j * BN + row];
        T += Tp[(size_t)j * BN + row];
    }
    float tau = temp[0];
    float E  = __logf(S) - T / S;                  // entropy (sans +1e-6, bias<4e-3)
    float cs = 1.0f / (1.0f + __expf((E - tgt[0]) / tau));

    const float4* F4 = (const float4*)(feat + (size_t)row * DIM);
    float4*       O4 = (float4*)(out + (size_t)row * DIM);
    float4 v0 = F4[lane], v1 = F4[lane + 64];
    v0.x *= cs; v0.y *= cs; v0.z *= cs; v0.w *= cs;
    v1.x *= cs; v1.y *= cs; v1.z *= cs; v1.w *= cs;
    O4[lane] = v0; O4[lane + 64] = v1;
    if (lane == 0) out[(size_t)BN * DIM + row] = cs;
}

extern "C" void kernel_launch(void* const* d_in, const int* in_sizes, int n_in,
                              void* d_out, int out_size, void* d_ws, size_t ws_size,
                              hipStream_t stream) {
    const float* feat = (const float*)d_in[0];
    const float* tgt  = (const float*)d_in[7];   // target_entropy
    const float* temp = (const float*)d_in[8];   // temperature
    float* out = (float*)d_out;

    char* ws = (char*)d_ws;
    uint8_t* fb = (uint8_t*)ws;                              // fp8 features, 8.4MB
    float*   sq = (float*)(ws + (size_t)BN * DIM);           // quantized row sumsq, 64KB
    float*   Sp = (float*)(ws + (size_t)BN * DIM + BN * 4);  // partial S, JSPLIT slices
    float*   Tp = Sp + (size_t)JSPLIT * BN;                  // partial T, JSPLIT slices

    prep_kernel<<<dim3(BN / 4), dim3(256), 0, stream>>>(feat, fb, sq);
    entropy_kernel<<<dim3(N_TOK / IPB, BATCH, JSPLIT), dim3(256), 0, stream>>>(fb, sq, temp, Sp, Tp);
    finalize_kernel<<<dim3(BN / 4), dim3(256), 0, stream>>>(feat, Sp, Tp, tgt, temp, out);
}

// Round 7
// 184.987 us; speedup vs baseline: 1.7008x; 1.7008x over previous
//
#include <hip/hip_runtime.h>
#include <stdint.h>

#define N_TOK 4096
#define DIM   512
#define BATCH 4
#define BN    (BATCH * N_TOK)
#define JSPLIT 16
#define JT    32                      // j-tile rows
#define IPW   64                      // i-rows per wave
#define IPB   256                     // i-rows per block (4 waves)
#define JITERS (N_TOK / JSPLIT / JT)  // 8

typedef __attribute__((ext_vector_type(4))) float f32x4;

// ---------- kernel 1: fp32 -> fp8(e4m3) convert + per-row sumsq of QUANTIZED values ----------
// sq from quantized values => diagonal d_ii ~ 0 exactly, matching ref's k_ii = 1.
__global__ __launch_bounds__(256) void prep_kernel(
    const float* __restrict__ feat, uint8_t* __restrict__ fb, float* __restrict__ sq)
{
    int row  = (blockIdx.x << 2) + (threadIdx.x >> 6);   // 0..BN-1
    int lane = threadIdx.x & 63;
    const float4* src = (const float4*)(feat + (size_t)row * DIM);
    float4 v0 = src[lane * 2];
    float4 v1 = src[lane * 2 + 1];

    uint w01 = (uint)__builtin_amdgcn_cvt_pk_fp8_f32(v0.x, v0.y, 0, false);
    w01      = (uint)__builtin_amdgcn_cvt_pk_fp8_f32(v0.z, v0.w, (int)w01, true);
    uint w23 = (uint)__builtin_amdgcn_cvt_pk_fp8_f32(v1.x, v1.y, 0, false);
    w23      = (uint)__builtin_amdgcn_cvt_pk_fp8_f32(v1.z, v1.w, (int)w23, true);
    uint2 pk; pk.x = w01; pk.y = w23;
    ((uint2*)(fb + (size_t)row * DIM))[lane] = pk;

    float s = 0.f, f;
    f = __builtin_amdgcn_cvt_f32_fp8((int)w01, 0); s = fmaf(f, f, s);
    f = __builtin_amdgcn_cvt_f32_fp8((int)w01, 1); s = fmaf(f, f, s);
    f = __builtin_amdgcn_cvt_f32_fp8((int)w01, 2); s = fmaf(f, f, s);
    f = __builtin_amdgcn_cvt_f32_fp8((int)w01, 3); s = fmaf(f, f, s);
    f = __builtin_amdgcn_cvt_f32_fp8((int)w23, 0); s = fmaf(f, f, s);
    f = __builtin_amdgcn_cvt_f32_fp8((int)w23, 1); s = fmaf(f, f, s);
    f = __builtin_amdgcn_cvt_f32_fp8((int)w23, 2); s = fmaf(f, f, s);
    f = __builtin_amdgcn_cvt_f32_fp8((int)w23, 3); s = fmaf(f, f, s);

#pragma unroll
    for (int m = 32; m; m >>= 1) s += __shfl_xor(s, m);
    if (lane == 0) sq[row] = s;
}

// async DMA of a 2-row pair (2 x 512B) with XOR-8 16B-chunk swizzle on the GLOBAL side.
__device__ __forceinline__ void dma2(const uint8_t* g, uint8_t* l, int lane, int r)
{
    int loc = lane & 31, h = lane >> 5;
    int sw  = (r + h) & 7;
    const uint8_t* src = g + h * DIM + ((loc ^ sw) << 4);
    __builtin_amdgcn_global_load_lds(
        (const __attribute__((address_space(1))) void*)src,
        (__attribute__((address_space(3))) void*)l, 16, 0, 0);
}

// ---------- kernel 2: flash-style RBF entropy, fp8 MFMA ----------
// grid (N/256, B, 16) = 1024 blocks (4/CU). Occupancy comes from the GRID;
// __launch_bounds__ stays (256,2): the 128-VGPR A-residency is the design —
// (256,4) forced VGPR=64 and spilled afrag to scratch (575MB fetch, 3x slower).
// Wave: 64 i-rows resident (4 strips, 128 VGPR fp8 A), sweeps 32-row j-tiles
// => 64 MACs per LDS byte.  e = min(g/tau^2 - (sqi+sqj)/(2 tau^2), 0); k=exp(e).
__global__ __launch_bounds__(256, 2) void entropy_kernel(
    const uint8_t* __restrict__ fb, const float* __restrict__ sq,
    const float* __restrict__ temp,
    float* __restrict__ Sp, float* __restrict__ Tp)
{
    __shared__ __align__(16) uint8_t Bs[2][JT * DIM];    // 2 x 16KB double buffer

    const int t    = threadIdx.x;
    const int w    = t >> 6;
    const int lane = t & 63;
    const int q    = lane >> 4;
    const int c16  = lane & 15;
    const int q1   = q & 1, q2 = q >> 1;
    const int s8   = c16 & 7;

    const int batch  = blockIdx.y;
    const int jh     = blockIdx.z;
    const int iw     = blockIdx.x * IPB + w * IPW;
    const int jstart = jh * (N_TOK / JSPLIT);
    const size_t rowbase = (size_t)batch * N_TOK;

    const float tau    = temp[0];
    const float inv2t2 = 0.5f / (tau * tau);
    const float cg     = 1.0f / (tau * tau);

    // A fragments: 4 strips x 16 k-chunks, 8B fp8 each = 128 VGPR
    long afrag[4][16];
#pragma unroll
    for (int s = 0; s < 4; ++s) {
        const uint2* ap = (const uint2*)(fb + (rowbase + iw + s * 16 + c16) * DIM);
#pragma unroll
        for (int kc = 0; kc < 16; ++kc) {
            uint2 v = ap[kc * 4 + q];
            afrag[s][kc] = (long)(((unsigned long long)v.y << 32) | v.x);
        }
    }
    float pi[4][4];
#pragma unroll
    for (int s = 0; s < 4; ++s)
#pragma unroll
        for (int r = 0; r < 4; ++r)
            pi[s][r] = -sq[rowbase + iw + s * 16 + q * 4 + r] * inv2t2;

    float S[4][4], T[4][4];
#pragma unroll
    for (int s = 0; s < 4; ++s)
#pragma unroll
        for (int r = 0; r < 4; ++r) { S[s][r] = 0.f; T[s][r] = 0.f; }

    // stage tile 0 (each wave DMAs 4 row-pairs)
#pragma unroll
    for (int rr = 0; rr < 4; ++rr) {
        int r = w * 8 + rr * 2;
        dma2(fb + (rowbase + jstart + r) * DIM, &Bs[0][r * DIM], lane, r);
    }
    __syncthreads();

    int cur = 0;
    for (int it = 0; it < JITERS; ++it) {
        const int jb = jstart + it * JT;
        if (it + 1 < JITERS) {                            // async prefetch next tile
#pragma unroll
            for (int rr = 0; rr < 4; ++rr) {
                int r = w * 8 + rr * 2;
                dma2(fb + (rowbase + jb + JT + r) * DIM, &Bs[cur ^ 1][r * DIM], lane, r);
            }
        }
        float pj0 = -sq[rowbase + jb + c16] * inv2t2;
        float pj1 = -sq[rowbase + jb + 16 + c16] * inv2t2;

#pragma unroll
        for (int jsub = 0; jsub < 2; ++jsub) {
            const uint8_t* Brow = &Bs[cur][(jsub * 16 + c16) * DIM] + (q1 << 3);
            f32x4 acc[4] = {{0,0,0,0},{0,0,0,0},{0,0,0,0},{0,0,0,0}};
#pragma unroll
            for (int kc = 0; kc < 16; ++kc) {
                int off = ((kc * 2 + q2) ^ s8) << 4;      // phys 16B chunk, +q1*8 in Brow
                long b  = *(const long*)(Brow + off);
#pragma unroll
                for (int s = 0; s < 4; ++s)
                    acc[s] = __builtin_amdgcn_mfma_f32_16x16x32_fp8_fp8(
                                 afrag[s][kc], b, acc[s], 0, 0, 0);
            }
            float pj = jsub ? pj1 : pj0;
#pragma unroll
            for (int s = 0; s < 4; ++s)
#pragma unroll
                for (int r = 0; r < 4; ++r) {
                    float e = fminf(fmaf(acc[s][r], cg, pi[s][r] + pj), 0.f);
                    float k = __expf(e);
                    S[s][r] += k;
                    T[s][r] = fmaf(k, e, T[s][r]);
                }
        }
        __syncthreads();                                  // prefetch landed; cur reads done
        cur ^= 1;
    }

    // reduce over the 16 j-columns (c16 lanes)
#pragma unroll
    for (int m = 1; m < 16; m <<= 1)
#pragma unroll
        for (int s = 0; s < 4; ++s)
#pragma unroll
            for (int r = 0; r < 4; ++r) {
                S[s][r] += __shfl_xor(S[s][r], m);
                T[s][r] += __shfl_xor(T[s][r], m);
            }

    if (c16 == 0) {
#pragma unroll
        for (int s = 0; s < 4; ++s)
#pragma unroll
            for (int r = 0; r < 4; ++r) {
                size_t idx = (size_t)jh * BN + rowbase + iw + s * 16 + q * 4 + r;
                Sp[idx] = S[s][r];
                Tp[idx] = T[s][r];
            }
    }
}

// ---------- kernel 3: combine partials, entropy -> sigmoid -> scale features ----------
__global__ __launch_bounds__(256) void finalize_kernel(
    const float* __restrict__ feat, const float* __restrict__ Sp,
    const float* __restrict__ Tp, const float* __restrict__ tgt,
    const float* __restrict__ temp, float* __restrict__ out)
{
    int row  = (blockIdx.x << 2) + (threadIdx.x >> 6);   // global row 0..BN-1
    int lane = threadIdx.x & 63;
    float S = 0.0f, T = 0.0f;
#pragma unroll
    for (int j = 0; j < JSPLIT; ++j) {
        S += Sp[(size_t)j * BN + row];
        T += Tp[(size_t)j * BN + row];
    }
    float tau = temp[0];
    float E  = __logf(S) - T / S;                  // entropy (sans +1e-6, bias<4e-3)
    float cs = 1.0f / (1.0f + __expf((E - tgt[0]) / tau));

    const float4* F4 = (const float4*)(feat + (size_t)row * DIM);
    float4*       O4 = (float4*)(out + (size_t)row * DIM);
    float4 v0 = F4[lane], v1 = F4[lane + 64];
    v0.x *= cs; v0.y *= cs; v0.z *= cs; v0.w *= cs;
    v1.x *= cs; v1.y *= cs; v1.z *= cs; v1.w *= cs;
    O4[lane] = v0; O4[lane + 64] = v1;
    if (lane == 0) out[(size_t)BN * DIM + row] = cs;
}

extern "C" void kernel_launch(void* const* d_in, const int* in_sizes, int n_in,
                              void* d_out, int out_size, void* d_ws, size_t ws_size,
                              hipStream_t stream) {
    const float* feat = (const float*)d_in[0];
    const float* tgt  = (const float*)d_in[7];   // target_entropy
    const float* temp = (const float*)d_in[8];   // temperature
    float* out = (float*)d_out;

    char* ws = (char*)d_ws;
    uint8_t* fb = (uint8_t*)ws;                              // fp8 features, 8.4MB
    float*   sq = (float*)(ws + (size_t)BN * DIM);           // quantized row sumsq, 64KB
    float*   Sp = (float*)(ws + (size_t)BN * DIM + BN * 4);  // partial S, JSPLIT slices
    float*   Tp = Sp + (size_t)JSPLIT * BN;                  // partial T, JSPLIT slices

    prep_kernel<<<dim3(BN / 4), dim3(256), 0, stream>>>(feat, fb, sq);
    entropy_kernel<<<dim3(N_TOK / IPB, BATCH, JSPLIT), dim3(256), 0, stream>>>(fb, sq, temp, Sp, Tp);
    finalize_kernel<<<dim3(BN / 4), dim3(256), 0, stream>>>(feat, Sp, Tp, tgt, temp, out);
}

// Round 8
// 173.929 us; speedup vs baseline: 1.8090x; 1.0636x over previous
//
#include <hip/hip_runtime.h>
#include <stdint.h>

#define N_TOK 4096
#define DIM   512
#define BATCH 4
#define BN    (BATCH * N_TOK)
#define JSPLIT 8
#define IPW   64                      // i-rows per wave (A resident in regs)
#define IPB   256                     // i-rows per block (4 waves)
#define NG    (N_TOK / JSPLIT / 16)   // 32 j-groups of 16 per slice

typedef __attribute__((ext_vector_type(4))) float f32x4;

__device__ __forceinline__ float sumsq8(uint lo, uint hi) {
    float s = 0.f, f;
    f = __builtin_amdgcn_cvt_f32_fp8((int)lo, 0); s = fmaf(f, f, s);
    f = __builtin_amdgcn_cvt_f32_fp8((int)lo, 1); s = fmaf(f, f, s);
    f = __builtin_amdgcn_cvt_f32_fp8((int)lo, 2); s = fmaf(f, f, s);
    f = __builtin_amdgcn_cvt_f32_fp8((int)lo, 3); s = fmaf(f, f, s);
    f = __builtin_amdgcn_cvt_f32_fp8((int)hi, 0); s = fmaf(f, f, s);
    f = __builtin_amdgcn_cvt_f32_fp8((int)hi, 1); s = fmaf(f, f, s);
    f = __builtin_amdgcn_cvt_f32_fp8((int)hi, 2); s = fmaf(f, f, s);
    f = __builtin_amdgcn_cvt_f32_fp8((int)hi, 3); s = fmaf(f, f, s);
    return s;
}

// ---------- prep: fp8 convert -> fb (row-major, A-side) + fbT (B-operand-transposed)
//            + per-row sumsq of QUANTIZED values.
// block 256 thr = one 16-row j-group; thread t: row16 = t>>4, 32-float segment seg = t&15.
// fbT layout per group: [kc 0..15][q 0..3][row16 0..15] x 8B  => per-kc wave B-load is
// one contiguous 512B global_load_dwordx2 in entropy_kernel.
__global__ __launch_bounds__(256) void prep_kernel(
    const float* __restrict__ feat, uint8_t* __restrict__ fb,
    uint8_t* __restrict__ fbT, float* __restrict__ sq)
{
    __shared__ __align__(8) uint2 lt[1024];        // [chunk 0..63][row16 0..15], swizzled
    const int t = threadIdx.x;
    const int row16 = t >> 4, seg = t & 15;
    const size_t grp = blockIdx.x;
    const size_t row = grp * 16 + row16;

    const float4* src = (const float4*)(feat + row * DIM + seg * 32);
    uint32_t wd[8];
    float s = 0.f;
#pragma unroll
    for (int i = 0; i < 4; ++i) {
        float4 a = src[2 * i], b = src[2 * i + 1];
        uint lo = (uint)__builtin_amdgcn_cvt_pk_fp8_f32(a.x, a.y, 0, false);
        lo      = (uint)__builtin_amdgcn_cvt_pk_fp8_f32(a.z, a.w, (int)lo, true);
        uint hi = (uint)__builtin_amdgcn_cvt_pk_fp8_f32(b.x, b.y, 0, false);
        hi      = (uint)__builtin_amdgcn_cvt_pk_fp8_f32(b.z, b.w, (int)hi, true);
        wd[2 * i] = lo; wd[2 * i + 1] = hi;
        s += sumsq8(lo, hi);
    }

    // row-major fb (A-side reads)
    uint4* dst = (uint4*)(fb + row * DIM + seg * 32);
    uint4 o0; o0.x = wd[0]; o0.y = wd[1]; o0.z = wd[2]; o0.w = wd[3];
    uint4 o1; o1.x = wd[4]; o1.y = wd[5]; o1.z = wd[6]; o1.w = wd[7];
    dst[0] = o0; dst[1] = o1;

    // transpose via LDS: chunk c = seg*4+i (8B each), swizzled to soften bank conflicts
#pragma unroll
    for (int i = 0; i < 4; ++i) {
        int c = seg * 4 + i;
        uint2 d; d.x = wd[2 * i]; d.y = wd[2 * i + 1];
        lt[c * 16 + ((row16 + c) & 15)] = d;
    }

    // sumsq reduce across the 16 seg-lanes (groups are 16-lane aligned)
#pragma unroll
    for (int m = 1; m < 16; m <<= 1) s += __shfl_xor(s, m);
    if (seg == 0) sq[row] = s;

    __syncthreads();
    uint2* ot = (uint2*)(fbT + grp * 8192);
#pragma unroll
    for (int i = 0; i < 4; ++i) {
        int p = t + i * 256;                       // p = chunk*16 + r16, coalesced out
        int c = p >> 4, r = p & 15;
        ot[p] = lt[c * 16 + ((r + c) & 15)];
    }
}

// ---------- entropy: register-resident A (64 i-rows/wave), register B from fbT ----------
// grid (N/256, B, 8) = 512 blocks, 256 thr = 4 independent waves. NO LDS, NO barriers
// in the hot loop: per j-group = 16 coalesced 8B/lane loads + 64 MFMAs + exp-skip tail.
// e = g/tau^2 - (sqi+sqj)/(2 tau^2); all-off-diag groups have e < -110 -> k==0 exactly
// in fp32 (ref too) -> skip exp/accumulate entirely (branch taken only near diagonal).
__global__ __launch_bounds__(256, 2) void entropy_kernel(
    const uint8_t* __restrict__ fb, const uint8_t* __restrict__ fbT,
    const float* __restrict__ sq, const float* __restrict__ temp,
    float* __restrict__ Sp, float* __restrict__ Tp)
{
    const int t    = threadIdx.x;
    const int w    = t >> 6;
    const int lane = t & 63;
    const int q    = lane >> 4;
    const int c16  = lane & 15;

    const int batch = blockIdx.y;
    const int jh    = blockIdx.z;
    const int iw    = blockIdx.x * IPB + w * IPW;
    const size_t rowbase = (size_t)batch * N_TOK;

    const float tau    = temp[0];
    const float inv2t2 = 0.5f / (tau * tau);
    const float cg     = 1.0f / (tau * tau);

    // A fragments: 4 strips x 16 k-chunks x 8B = 128 VGPR, from row-major fb
    long afrag[4][16];
#pragma unroll
    for (int s = 0; s < 4; ++s) {
        const long* ap = (const long*)(fb + (rowbase + iw + s * 16 + c16) * DIM);
#pragma unroll
        for (int kc = 0; kc < 16; ++kc) afrag[s][kc] = ap[kc * 4 + q];
    }
    float pi[4][4];
#pragma unroll
    for (int s = 0; s < 4; ++s)
#pragma unroll
        for (int r = 0; r < 4; ++r)
            pi[s][r] = -sq[rowbase + iw + s * 16 + q * 4 + r] * inv2t2;

    float S[4][4], T[4][4];
#pragma unroll
    for (int s = 0; s < 4; ++s)
#pragma unroll
        for (int r = 0; r < 4; ++r) { S[s][r] = 0.f; T[s][r] = 0.f; }

    // per-lane B pointer into fbT: group-major, [kc][q][r16] inside each 8KB group
    const long*  bp  = (const long*)fbT
                     + ((size_t)batch * (N_TOK / 16) + (size_t)jh * NG) * 1024
                     + q * 16 + c16;
    const float* sqj = sq + rowbase + jh * (N_TOK / JSPLIT) + c16;

    for (int g = 0; g < NG; ++g) {
        float pj = -sqj[g * 16] * inv2t2;
        const long* bg = bp + (size_t)g * 1024;
        f32x4 acc[4] = {{0,0,0,0},{0,0,0,0},{0,0,0,0},{0,0,0,0}};
#pragma unroll
        for (int kc = 0; kc < 16; ++kc) {
            long b = bg[kc * 64];                  // coalesced 512B wave load
#pragma unroll
            for (int s = 0; s < 4; ++s)
                acc[s] = __builtin_amdgcn_mfma_f32_16x16x32_fp8_fp8(
                             afrag[s][kc], b, acc[s], 0, 0, 0);
        }
        float e[4][4], m = -1e30f;
#pragma unroll
        for (int s = 0; s < 4; ++s)
#pragma unroll
            for (int r = 0; r < 4; ++r) {
                e[s][r] = fmaf(acc[s][r], cg, pi[s][r] + pj);
                m = fmaxf(m, e[s][r]);
            }
        if (m > -110.0f) {                         // rare: only diagonal-adjacent groups
#pragma unroll
            for (int s = 0; s < 4; ++s)
#pragma unroll
                for (int r = 0; r < 4; ++r) {
                    float ee = fminf(e[s][r], 0.f);
                    float k  = __expf(ee);
                    S[s][r] += k;
                    T[s][r]  = fmaf(k, ee, T[s][r]);
                }
        }
    }

    // reduce over the 16 j-columns (c16 lanes)
#pragma unroll
    for (int m = 1; m < 16; m <<= 1)
#pragma unroll
        for (int s = 0; s < 4; ++s)
#pragma unroll
            for (int r = 0; r < 4; ++r) {
                S[s][r] += __shfl_xor(S[s][r], m);
                T[s][r] += __shfl_xor(T[s][r], m);
            }

    if (c16 == 0) {
#pragma unroll
        for (int s = 0; s < 4; ++s)
#pragma unroll
            for (int r = 0; r < 4; ++r) {
                size_t idx = (size_t)jh * BN + rowbase + iw + s * 16 + q * 4 + r;
                Sp[idx] = S[s][r];
                Tp[idx] = T[s][r];
            }
    }
}

// ---------- finalize: combine partials, entropy -> sigmoid -> scale features ----------
__global__ __launch_bounds__(256) void finalize_kernel(
    const float* __restrict__ feat, const float* __restrict__ Sp,
    const float* __restrict__ Tp, const float* __restrict__ tgt,
    const float* __restrict__ temp, float* __restrict__ out)
{
    int row  = (blockIdx.x << 2) + (threadIdx.x >> 6);   // global row 0..BN-1
    int lane = threadIdx.x & 63;
    float S = 0.0f, T = 0.0f;
#pragma unroll
    for (int j = 0; j < JSPLIT; ++j) {
        S += Sp[(size_t)j * BN + row];
        T += Tp[(size_t)j * BN + row];
    }
    float tau = temp[0];
    float E  = __logf(S) - T / S;                  // entropy (sans +1e-6, bias<4e-3)
    float cs = 1.0f / (1.0f + __expf((E - tgt[0]) / tau));

    const float4* F4 = (const float4*)(feat + (size_t)row * DIM);
    float4*       O4 = (float4*)(out + (size_t)row * DIM);
    float4 v0 = F4[lane], v1 = F4[lane + 64];
    v0.x *= cs; v0.y *= cs; v0.z *= cs; v0.w *= cs;
    v1.x *= cs; v1.y *= cs; v1.z *= cs; v1.w *= cs;
    O4[lane] = v0; O4[lane + 64] = v1;
    if (lane == 0) out[(size_t)BN * DIM + row] = cs;
}

extern "C" void kernel_launch(void* const* d_in, const int* in_sizes, int n_in,
                              void* d_out, int out_size, void* d_ws, size_t ws_size,
                              hipStream_t stream) {
    const float* feat = (const float*)d_in[0];
    const float* tgt  = (const float*)d_in[7];   // target_entropy
    const float* temp = (const float*)d_in[8];   // temperature
    float* out = (float*)d_out;

    char* ws = (char*)d_ws;
    uint8_t* fb  = (uint8_t*)ws;                               // fp8 row-major, 8.4MB
    uint8_t* fbT = fb + (size_t)BN * DIM;                      // fp8 B-transposed, 8.4MB
    float*   sq  = (float*)(fbT + (size_t)BN * DIM);           // quantized row sumsq
    float*   Sp  = sq + BN;                                    // partial S, JSPLIT slices
    float*   Tp  = Sp + (size_t)JSPLIT * BN;                   // partial T, JSPLIT slices

    prep_kernel<<<dim3(BN / 16), dim3(256), 0, stream>>>(feat, fb, fbT, sq);
    entropy_kernel<<<dim3(N_TOK / IPB, BATCH, JSPLIT), dim3(256), 0, stream>>>(fb, fbT, sq, temp, Sp, Tp);
    finalize_kernel<<<dim3(BN / 4), dim3(256), 0, stream>>>(feat, Sp, Tp, tgt, temp, out);
}